// Round 1
// baseline (70.963 us; speedup 1.0000x reference)
//
#include <hip/hip_runtime.h>
#include <math.h>

// Compile-time double-precision constants (folded by the compiler).
namespace {
constexpr double D_SUN    = 149600000.0;
constexpr double D_VT_REF = 2.5 * 8.617333262e-05 * 298.15;   // N*kB/q*T_ref
constexpr double D_Z0     = 2.35 / D_VT_REF;                  // VOC_CELL / vt_ref
constexpr double D_AREA_A = 0.0604 * 0.0398;
constexpr double D_AREA_B = 0.0403 * 0.0306;
constexpr double D_NKB    = 2.5 * 8.617333262e-05;            // N*kB/q
}

#define NITER 25

__global__ __launch_bounds__(256) void spm_kernel(
    const float* __restrict__ x,
    const float* __restrict__ fxn, const float* __restrict__ fyn,
    const float* __restrict__ fxp, const float* __restrict__ fyp,
    float* __restrict__ out, int N)
{
  __shared__ float lds[256 * 11];
  const int tid  = threadIdx.x;
  const int row0 = blockIdx.x * 256;
  const int nrows = min(256, N - row0);
  const int nf = nrows * 11;
  const float* src = x + (long long)row0 * 11;
  // Coalesced global -> LDS staging of the block's 256 rows (11 f32 each).
  for (int k = tid; k < nf; k += 256) lds[k] = src[k];
  __syncthreads();
  if (tid >= nrows) return;

  const float* r = &lds[tid * 11];   // stride 11 (odd) -> bank-conflict-free
  const float sx  = r[0], sy  = r[1];
  const float tpx = r[2], tnx = r[3], tpy = r[4], tny = r[5];
  const float V   = r[6], dist = r[7];

  const float ratio = (float)D_SUN / dist;
  const float irr   = 1366.0f * ratio * ratio;
  const float vcell = V / 18.0f;                 // all configs have series=18

  const float gyn = irr * fmaxf(-sy, 0.0f);
  const float gxn = irr * fmaxf(-sx, 0.0f);
  const float gxp = irr * fmaxf( sx, 0.0f);
  const float gyp = irr * fmaxf( sy, 0.0f);

  const float i0fac = 170.0f / expm1f((float)D_Z0);
  const float i0A = i0fac * (float)D_AREA_A;
  const float i0B = i0fac * (float)D_AREA_B;

  // Six sub-config solves: {Y_NEG A, X_NEG A, X_NEG B, X_POS A, X_POS B, Y_POS B}
  const float G[6]   = {gyn, gxn, gxn, gxp, gxp, gyp};
  const float Tt[6]  = {tny, tnx, tnx, tpx, tpx, tpy};
  const float i0v[6] = {i0A, i0A, i0B, i0A, i0B, i0B};
  const float areav[6] = {(float)D_AREA_A, (float)D_AREA_A, (float)D_AREA_B,
                          (float)D_AREA_A, (float)D_AREA_B, (float)D_AREA_B};

  float I[6], iph_pi0[6], inv_vt[6], c1[6];
  #pragma unroll
  for (int s = 0; s < 6; ++s) {
    float iph = 170.0f * areav[s] * (G[s] / 1366.0f)
              * (1.0f + 6.0e-4f * (Tt[s] - 298.15f));
    float vt  = (float)D_NKB * Tt[s];
    inv_vt[s] = 1.0f / vt;
    c1[s]     = i0v[s] * 0.01f * inv_vt[s];  // i0*RS/vt
    iph_pi0[s]= iph + i0v[s];
    I[s]      = iph;
  }
  const float C2      = 1.0f + 0.01f / 500.0f;  // RS/RSH + 1  (= -fp linear part)
  const float INV_RSH = 1.0f / 500.0f;
  const float L2E     = 1.4426950408889634f;

  // 25 Newton iterations; 6 independent solves interleaved for ILP.
  #pragma unroll 1
  for (int it = 0; it < NITER; ++it) {
    #pragma unroll
    for (int s = 0; s < 6; ++s) {
      float w = fmaf(I[s], 0.01f, vcell);          // v_cell + I*RS
      float z = w * inv_vt[s];
      z = fminf(fmaxf(z, -40.0f), 40.0f);
      float e = __builtin_amdgcn_exp2f(z * L2E);   // exp(z)
      float f = fmaf(-i0v[s], e, iph_pi0[s]);      // iph - i0*(e-1)
      f = fmaf(-INV_RSH, w, f) - I[s];             // - w/RSH - I
      float nfp = fmaf(c1[s], e, C2);              // = -fp (>0, ~1.0003)
      I[s] = fmaf(f, __builtin_amdgcn_rcpf(nfp), I[s]);  // I - f/fp
    }
  }

  const float ixn = 2.0f * fmaxf(I[1], 0.0f) + 7.0f * fmaxf(I[2], 0.0f);
  const float iyn = 6.0f * fmaxf(I[0], 0.0f);
  const float ixp = 2.0f * fmaxf(I[3], 0.0f) + 7.0f * fmaxf(I[4], 0.0f);
  const float iyp = 10.0f * fmaxf(I[5], 0.0f);
  const float tot = (ixn * fxn[0] + iyn * fyn[0]
                   + ixp * fxp[0] + iyp * fyp[0]) * 0.92f;
  out[row0 + tid] = tot;
}

extern "C" void kernel_launch(void* const* d_in, const int* in_sizes, int n_in,
                              void* d_out, int out_size, void* d_ws, size_t ws_size,
                              hipStream_t stream) {
  const float* x   = (const float*)d_in[0];
  const float* fxn = (const float*)d_in[1];
  const float* fyn = (const float*)d_in[2];
  const float* fxp = (const float*)d_in[3];
  const float* fyp = (const float*)d_in[4];
  float* out = (float*)d_out;
  const int N = in_sizes[0] / 11;
  const int blocks = (N + 255) / 256;
  spm_kernel<<<blocks, 256, 0, stream>>>(x, fxn, fyn, fxp, fyp, out, N);
}

// Round 3
// 65.662 us; speedup vs baseline: 1.0807x; 1.0807x over previous
//
#include <hip/hip_runtime.h>
#include <math.h>

// Compile-time double-precision constants (folded by the compiler).
namespace {
constexpr double D_SUN    = 149600000.0;
constexpr double D_VT_REF = 2.5 * 8.617333262e-05 * 298.15;   // N*kB/q*T_ref
constexpr double D_Z0     = 2.35 / D_VT_REF;                  // VOC_CELL / vt_ref
constexpr double D_AREA_A = 0.0604 * 0.0398;
constexpr double D_AREA_B = 0.0403 * 0.0306;
constexpr double D_NKB    = 2.5 * 8.617333262e-05;            // N*kB/q
}

// Newton is quadratically convergent and the residual is nearly linear here
// (f' ~= -1.0003: diode term i0*e^z <= ~1.5e-3 A since vcell << VOC).
// From I=iph it converges to f32 precision in <=3 iters; 8 is bulletproof.
#define NITER 8

__global__ __launch_bounds__(256) void spm_kernel(
    const float* __restrict__ x,
    const float* __restrict__ fxn, const float* __restrict__ fyn,
    const float* __restrict__ fxp, const float* __restrict__ fyp,
    float* __restrict__ out, int N)
{
  __shared__ float lds[256 * 11];
  const int tid  = threadIdx.x;
  const int row0 = blockIdx.x * 256;
  const int nrows = min(256, N - row0);
  const int nf = nrows * 11;
  const float* src = x + (long long)row0 * 11;
  // Coalesced global -> LDS staging of the block's 256 rows (11 f32 each).
  for (int k = tid; k < nf; k += 256) lds[k] = src[k];
  __syncthreads();
  if (tid >= nrows) return;

  const float* r = &lds[tid * 11];   // stride 11 (odd) -> bank-conflict-free
  const float sx  = r[0], sy  = r[1];
  const float tpx = r[2], tnx = r[3], tpy = r[4], tny = r[5];
  const float V   = r[6], dist = r[7];

  const float ratio = (float)D_SUN / dist;
  const float irr   = 1366.0f * ratio * ratio;
  const float vcell = V / 18.0f;                 // all configs have series=18

  const float gyn = irr * fmaxf(-sy, 0.0f);
  const float gxn = irr * fmaxf(-sx, 0.0f);
  const float gxp = irr * fmaxf( sx, 0.0f);
  const float gyp = irr * fmaxf( sy, 0.0f);

  const float i0fac = 170.0f / expm1f((float)D_Z0);
  const float i0A = i0fac * (float)D_AREA_A;
  const float i0B = i0fac * (float)D_AREA_B;

  // Six sub-config solves: {Y_NEG A, X_NEG A, X_NEG B, X_POS A, X_POS B, Y_POS B}
  const float G[6]   = {gyn, gxn, gxn, gxp, gxp, gyp};
  const float Tt[6]  = {tny, tnx, tnx, tpx, tpx, tpy};
  const float i0v[6] = {i0A, i0A, i0B, i0A, i0B, i0B};
  const float areav[6] = {(float)D_AREA_A, (float)D_AREA_A, (float)D_AREA_B,
                          (float)D_AREA_A, (float)D_AREA_B, (float)D_AREA_B};

  const float L2E = 1.4426950408889634f;
  float I[6], iph_pi0[6], ivt_l2e[6], inv_vt[6], c1[6];
  #pragma unroll
  for (int s = 0; s < 6; ++s) {
    float iph = 170.0f * areav[s] * (G[s] / 1366.0f)
              * (1.0f + 6.0e-4f * (Tt[s] - 298.15f));
    float vt  = (float)D_NKB * Tt[s];
    inv_vt[s] = 1.0f / vt;
    ivt_l2e[s]= inv_vt[s] * L2E;            // exp(z) = exp2(w*inv_vt*L2E)
    c1[s]     = i0v[s] * 0.01f * inv_vt[s]; // i0*RS/vt
    iph_pi0[s]= iph + i0v[s];
    I[s]      = iph;
  }
  const float C2      = 1.0f + 0.01f / 500.0f;  // RS/RSH + 1  (= -fp linear part)
  const float INV_RSH = 1.0f / 500.0f;
  const float ZCLIP   = 40.0f * L2E;            // clip in log2 domain

  // Newton iterations; 6 independent solves interleaved for ILP.
  #pragma unroll 1
  for (int it = 0; it < NITER; ++it) {
    #pragma unroll
    for (int s = 0; s < 6; ++s) {
      float w  = fmaf(I[s], 0.01f, vcell);          // v_cell + I*RS
      float z2 = w * ivt_l2e[s];                    // z*log2(e)
      z2 = fminf(fmaxf(z2, -ZCLIP), ZCLIP);
      float e = __builtin_amdgcn_exp2f(z2);         // exp(z)
      float f = fmaf(-i0v[s], e, iph_pi0[s]);       // iph - i0*(e-1)
      f = fmaf(-INV_RSH, w, f) - I[s];              // - w/RSH - I
      float nfp = fmaf(c1[s], e, C2);               // = -fp (>0, ~1.0003)
      I[s] = fmaf(f, __builtin_amdgcn_rcpf(nfp), I[s]);  // I - f/fp
    }
  }

  const float ixn = 2.0f * fmaxf(I[1], 0.0f) + 7.0f * fmaxf(I[2], 0.0f);
  const float iyn = 6.0f * fmaxf(I[0], 0.0f);
  const float ixp = 2.0f * fmaxf(I[3], 0.0f) + 7.0f * fmaxf(I[4], 0.0f);
  const float iyp = 10.0f * fmaxf(I[5], 0.0f);
  const float tot = (ixn * fxn[0] + iyn * fyn[0]
                   + ixp * fxp[0] + iyp * fyp[0]) * 0.92f;
  out[row0 + tid] = tot;
}

extern "C" void kernel_launch(void* const* d_in, const int* in_sizes, int n_in,
                              void* d_out, int out_size, void* d_ws, size_t ws_size,
                              hipStream_t stream) {
  const float* x   = (const float*)d_in[0];
  const float* fxn = (const float*)d_in[1];
  const float* fyn = (const float*)d_in[2];
  const float* fxp = (const float*)d_in[3];
  const float* fyp = (const float*)d_in[4];
  float* out = (float*)d_out;
  const int N = in_sizes[0] / 11;
  const int blocks = (N + 255) / 256;
  spm_kernel<<<blocks, 256, 0, stream>>>(x, fxn, fyn, fxp, fyp, out, N);
}

// Round 4
// 65.023 us; speedup vs baseline: 1.0914x; 1.0098x over previous
//
#include <hip/hip_runtime.h>
#include <math.h>

// Compile-time double-precision constants (folded by the compiler).
namespace {
constexpr double D_SUN    = 149600000.0;
constexpr double D_VT_REF = 2.5 * 8.617333262e-05 * 298.15;   // N*kB/q*T_ref
constexpr double D_Z0     = 2.35 / D_VT_REF;                  // VOC_CELL / vt_ref
constexpr double D_AREA_A = 0.0604 * 0.0398;
constexpr double D_AREA_B = 0.0403 * 0.0306;
constexpr double D_NKB    = 2.5 * 8.617333262e-05;            // N*kB/q
}

// Convergence arithmetic: residual is nearly linear in I (f' ~= -1.0003;
// diode term i0*e^z <= ~1.5e-3 A since vcell <= 1.67 V << VOC=2.35 V).
// From I=iph: eps0 ~= 4.4e-3 A, eps1 ~= |f''/2f'|*eps0^2 ~= 5e-10 A < f32 ulp.
// 2 iterations are machine-converged; 3rd is margin. (absmax was 0.0 at 8.)
#define NITER 3

__global__ __launch_bounds__(256) void spm_kernel(
    const float* __restrict__ x,
    const float* __restrict__ fxn, const float* __restrict__ fyn,
    const float* __restrict__ fxp, const float* __restrict__ fyp,
    float* __restrict__ out, int N)
{
  __shared__ float lds[256 * 11];
  const int tid  = threadIdx.x;
  const int row0 = blockIdx.x * 256;
  const int nrows = min(256, N - row0);
  const int nf = nrows * 11;
  const float* src = x + (long long)row0 * 11;
  // Coalesced global -> LDS staging of the block's 256 rows (11 f32 each).
  for (int k = tid; k < nf; k += 256) lds[k] = src[k];
  __syncthreads();
  if (tid >= nrows) return;

  const float* r = &lds[tid * 11];   // stride 11 (odd) -> bank-conflict-free
  const float sx  = r[0], sy  = r[1];
  const float tpx = r[2], tnx = r[3], tpy = r[4], tny = r[5];
  const float V   = r[6], dist = r[7];

  const float ratio = (float)D_SUN / dist;
  const float irr   = 1366.0f * ratio * ratio;
  const float vcell = V / 18.0f;                 // all configs have series=18

  const float gyn = irr * fmaxf(-sy, 0.0f);
  const float gxn = irr * fmaxf(-sx, 0.0f);
  const float gxp = irr * fmaxf( sx, 0.0f);
  const float gyp = irr * fmaxf( sy, 0.0f);

  const float i0fac = 170.0f / expm1f((float)D_Z0);
  const float i0A = i0fac * (float)D_AREA_A;
  const float i0B = i0fac * (float)D_AREA_B;

  // Six sub-config solves: {Y_NEG A, X_NEG A, X_NEG B, X_POS A, X_POS B, Y_POS B}
  const float G[6]   = {gyn, gxn, gxn, gxp, gxp, gyp};
  const float Tt[6]  = {tny, tnx, tnx, tpx, tpx, tpy};
  const float i0v[6] = {i0A, i0A, i0B, i0A, i0B, i0B};
  const float areav[6] = {(float)D_AREA_A, (float)D_AREA_A, (float)D_AREA_B,
                          (float)D_AREA_A, (float)D_AREA_B, (float)D_AREA_B};

  const float L2E = 1.4426950408889634f;
  float I[6], iph_pi0[6], ivt_l2e[6], inv_vt[6], c1[6];
  #pragma unroll
  for (int s = 0; s < 6; ++s) {
    float iph = 170.0f * areav[s] * (G[s] / 1366.0f)
              * (1.0f + 6.0e-4f * (Tt[s] - 298.15f));
    float vt  = (float)D_NKB * Tt[s];
    inv_vt[s] = 1.0f / vt;
    ivt_l2e[s]= inv_vt[s] * L2E;            // exp(z) = exp2(w*inv_vt*L2E)
    c1[s]     = i0v[s] * 0.01f * inv_vt[s]; // i0*RS/vt
    iph_pi0[s]= iph + i0v[s];
    I[s]      = iph;
  }
  const float C2      = 1.0f + 0.01f / 500.0f;  // RS/RSH + 1  (= -fp linear part)
  const float INV_RSH = 1.0f / 500.0f;
  const float ZCLIP   = 40.0f * L2E;            // clip in log2 domain (never
                                                // binds: |z| <= ~31 < 40)

  // Newton iterations; 6 independent solves interleaved for ILP.
  #pragma unroll 1
  for (int it = 0; it < NITER; ++it) {
    #pragma unroll
    for (int s = 0; s < 6; ++s) {
      float w  = fmaf(I[s], 0.01f, vcell);          // v_cell + I*RS
      float z2 = w * ivt_l2e[s];                    // z*log2(e)
      z2 = fminf(fmaxf(z2, -ZCLIP), ZCLIP);
      float e = __builtin_amdgcn_exp2f(z2);         // exp(z)
      float f = fmaf(-i0v[s], e, iph_pi0[s]);       // iph - i0*(e-1)
      f = fmaf(-INV_RSH, w, f) - I[s];              // - w/RSH - I
      float nfp = fmaf(c1[s], e, C2);               // = -fp (>0, ~1.0003)
      I[s] = fmaf(f, __builtin_amdgcn_rcpf(nfp), I[s]);  // I - f/fp
    }
  }

  const float ixn = 2.0f * fmaxf(I[1], 0.0f) + 7.0f * fmaxf(I[2], 0.0f);
  const float iyn = 6.0f * fmaxf(I[0], 0.0f);
  const float ixp = 2.0f * fmaxf(I[3], 0.0f) + 7.0f * fmaxf(I[4], 0.0f);
  const float iyp = 10.0f * fmaxf(I[5], 0.0f);
  const float tot = (ixn * fxn[0] + iyn * fyn[0]
                   + ixp * fxp[0] + iyp * fyp[0]) * 0.92f;
  out[row0 + tid] = tot;
}

extern "C" void kernel_launch(void* const* d_in, const int* in_sizes, int n_in,
                              void* d_out, int out_size, void* d_ws, size_t ws_size,
                              hipStream_t stream) {
  const float* x   = (const float*)d_in[0];
  const float* fxn = (const float*)d_in[1];
  const float* fyn = (const float*)d_in[2];
  const float* fxp = (const float*)d_in[3];
  const float* fyp = (const float*)d_in[4];
  float* out = (float*)d_out;
  const int N = in_sizes[0] / 11;
  const int blocks = (N + 255) / 256;
  spm_kernel<<<blocks, 256, 0, stream>>>(x, fxn, fyn, fxp, fyp, out, N);
}